// Round 7
// baseline (561.009 us; speedup 1.0000x reference)
//
#include <hip/hip_runtime.h>
#include <stdint.h>

// ---------------------------------------------------------------------------
// Threefry-2x32 (20 rounds) — exact JAX semantics.
// ---------------------------------------------------------------------------
__host__ __device__ inline void tf2x32(unsigned k0, unsigned k1,
                                       unsigned& x0, unsigned& x1) {
  unsigned k2 = k0 ^ k1 ^ 0x1BD11BDAu;
  x0 += k0; x1 += k1;
#define TFR(r) { x0 += x1; x1 = (x1 << (r)) | (x1 >> (32 - (r))); x1 ^= x0; }
  TFR(13) TFR(15) TFR(26) TFR(6)
  x0 += k1; x1 += k2 + 1u;
  TFR(17) TFR(29) TFR(16) TFR(24)
  x0 += k2; x1 += k0 + 2u;
  TFR(13) TFR(15) TFR(26) TFR(6)
  x0 += k0; x1 += k1 + 3u;
  TFR(17) TFR(29) TFR(16) TFR(24)
  x0 += k1; x1 += k2 + 4u;
  TFR(13) TFR(15) TFR(26) TFR(6)
  x0 += k2; x1 += k0 + 5u;
#undef TFR
}

__device__ __forceinline__ float drop_scale(unsigned k0, unsigned k1, unsigned f) {
  unsigned a = 0u, b = f;
  tf2x32(k0, k1, a, b);
  unsigned bits = a ^ b;
  float u = __uint_as_float((bits >> 9) | 0x3f800000u) - 1.0f;
  return (u < 0.8f) ? 1.25f : 0.0f;
}

// fp32 -> bf16 (round-to-nearest-even), and unpack helpers
__device__ __forceinline__ unsigned f2bf(float x) {
  unsigned u = __float_as_uint(x);
  return (u + 0x7fffu + ((u >> 16) & 1u)) >> 16;
}
__device__ __forceinline__ float bf_lo(unsigned u) {         // even col
  return __uint_as_float(u << 16);
}
__device__ __forceinline__ float bf_hi(unsigned u) {         // odd col
  return __uint_as_float(u & 0xffff0000u);
}

// ---------------------------------------------------------------------------
// CSR build: count+rank -> scan -> atomic-free fill
// ---------------------------------------------------------------------------
__global__ __launch_bounds__(256) void count_rank(
    const int* __restrict__ dst, int* __restrict__ cnt,
    int* __restrict__ rank, int e) {
  int i0 = (blockIdx.x * 256 + threadIdx.x) * 4;
  if (i0 + 3 < e) {
    int4 d4 = *(const int4*)&dst[i0];
    int4 r4;
    r4.x = atomicAdd(&cnt[d4.x], 1);
    r4.y = atomicAdd(&cnt[d4.y], 1);
    r4.z = atomicAdd(&cnt[d4.z], 1);
    r4.w = atomicAdd(&cnt[d4.w], 1);
    *(int4*)&rank[i0] = r4;
  } else {
    for (int i = i0; i < e; ++i)
      rank[i] = atomicAdd(&cnt[dst[i]], 1);
  }
}

// legacy fallback path (if ws too small for rank[]): batched cursor fill
__global__ __launch_bounds__(256) void fill_adj_cursor(
    const int* __restrict__ src, const int* __restrict__ dst,
    int* __restrict__ cursor, int* __restrict__ adj, int e) {
  int i0 = (blockIdx.x * 256 + threadIdx.x) * 4;
  for (int i = i0; i < min(i0 + 4, e); ++i) {
    int d = dst[i];
    int p = atomicAdd(&cursor[d], 1);
    adj[p] = src[i];
  }
}

// scan_local also emits dinv (deg includes self-loop)
__global__ void scan_local(const int* __restrict__ cnt, int* __restrict__ excl,
                           int* __restrict__ bsum, float* __restrict__ dinv, int n) {
  __shared__ int sh[512];
  int i = blockIdx.x * 512 + threadIdx.x;
  int v = (i < n) ? cnt[i] : 0;
  if (i < n) dinv[i] = 1.0f / sqrtf((float)v + 1.0f);
  sh[threadIdx.x] = v;
  __syncthreads();
  for (int d = 1; d < 512; d <<= 1) {
    int t = (threadIdx.x >= d) ? sh[threadIdx.x - d] : 0;
    __syncthreads();
    sh[threadIdx.x] += t;
    __syncthreads();
  }
  if (i < n) excl[i] = sh[threadIdx.x] - v;               // exclusive
  if (threadIdx.x == 511) bsum[blockIdx.x] = sh[511];     // block total
}

__global__ void scan_bsum(int* __restrict__ bsum, int nb) {
  __shared__ int sh[256];
  int tid = threadIdx.x;
  int v = (tid < nb) ? bsum[tid] : 0;
  sh[tid] = v;
  __syncthreads();
  for (int d = 1; d < 256; d <<= 1) {
    int t = (tid >= d) ? sh[tid - d] : 0;
    __syncthreads();
    sh[tid] += t;
    __syncthreads();
  }
  if (tid < nb) bsum[tid] = sh[tid] - v;                  // exclusive
}

__global__ void scan_final(const int* __restrict__ excl, const int* __restrict__ bsum,
                           int* __restrict__ rowptr, int* __restrict__ cursor,
                           int n, int e, int write_cursor) {
  int i = blockIdx.x * blockDim.x + threadIdx.x;
  if (i < n) {
    int r = excl[i] + bsum[i >> 9];
    rowptr[i] = r;
    if (write_cursor) cursor[i] = r;
  }
  if (i == n) rowptr[n] = e;
}

// atomic-free CSR fill: adj[rowptr[d] + rank[i]] = src[i], 8 edges/thread
__global__ __launch_bounds__(256) void fill_csr(
    const int* __restrict__ src, const int* __restrict__ dst,
    const int* __restrict__ rank, const int* __restrict__ rowptr,
    int* __restrict__ adj, int e) {
  int i0 = (blockIdx.x * 256 + threadIdx.x) * 8;
  if (i0 + 7 < e) {
    int4 d0 = *(const int4*)&dst[i0];
    int4 d1 = *(const int4*)&dst[i0 + 4];
    int4 r0 = *(const int4*)&rank[i0];
    int4 r1 = *(const int4*)&rank[i0 + 4];
    int4 s0 = *(const int4*)&src[i0];
    int4 s1 = *(const int4*)&src[i0 + 4];
    int p0 = rowptr[d0.x] + r0.x;
    int p1 = rowptr[d0.y] + r0.y;
    int p2 = rowptr[d0.z] + r0.z;
    int p3 = rowptr[d0.w] + r0.w;
    int p4 = rowptr[d1.x] + r1.x;
    int p5 = rowptr[d1.y] + r1.y;
    int p6 = rowptr[d1.z] + r1.z;
    int p7 = rowptr[d1.w] + r1.w;
    adj[p0] = s0.x; adj[p1] = s0.y; adj[p2] = s0.z; adj[p3] = s0.w;
    adj[p4] = s1.x; adj[p5] = s1.y; adj[p6] = s1.z; adj[p7] = s1.w;
  } else {
    for (int i = i0; i < e; ++i)
      adj[rowptr[dst[i]] + rank[i]] = src[i];
  }
}

// ---------------------------------------------------------------------------
// Fused GEMM: h'[r][c] = dinv[r] * sum_k relu(dropout(A[r][k])) * W[k][c]
// Output written as packed bf16 (RNE) — the pull kernels gather it.
// ---------------------------------------------------------------------------
template<int BM, int AP, int NCOLP, int NOUT>
__global__ __launch_bounds__(256) void gemm_drop(
    const float* __restrict__ A, const float* __restrict__ W,
    const float* __restrict__ dinv, unsigned short* __restrict__ Hout,
    int n, unsigned kd0, unsigned kd1)
{
  __shared__ float Ash[BM * AP];
  __shared__ float Wsh[128 * NCOLP];
  const int tid = threadIdx.x;
  const int r0 = blockIdx.x * BM;

  // stage W (zero-pad cols >= NOUT)
  if constexpr (NOUT == NCOLP) {
    for (int i = tid; i < 128 * NCOLP / 4; i += 256)
      *(float4*)&Wsh[i * 4] = *(const float4*)&W[i * 4];
  } else {
    for (int i = tid; i < 128 * NCOLP; i += 256) {
      int k = i / NCOLP, c = i % NCOLP;
      Wsh[i] = (c < NOUT) ? W[k * NOUT + c] : 0.0f;
    }
  }

  // stage A with fused dropout(threefry) + relu
  for (int i4 = tid; i4 < BM * 32; i4 += 256) {
    int rr = i4 >> 5;
    int k4 = (i4 & 31) << 2;
    int row = r0 + rr;
    float4 v = make_float4(0.f, 0.f, 0.f, 0.f);
    if (row < n) {
      v = *(const float4*)&A[(size_t)row * 128 + k4];
      unsigned fb = (unsigned)row * 128u + (unsigned)k4;
      float* pv = &v.x;
#pragma unroll
      for (int j = 0; j < 4; ++j)
        pv[j] = fmaxf(pv[j], 0.0f) * drop_scale(kd0, kd1, fb + j);
    }
    *(float4*)&Ash[rr * AP + k4] = v;
  }
  __syncthreads();

  constexpr int CG = NCOLP / 4;          // col groups (32 or 16)
  const int tx = tid % CG, ty = tid / CG;
  const int c0 = tx * 4;
  const int rl = ty * 4;
  float acc[4][4] = {};
  for (int k = 0; k < 128; k += 4) {
    float4 a[4];
#pragma unroll
    for (int i = 0; i < 4; ++i)
      a[i] = *(const float4*)&Ash[(rl + i) * AP + k];
#pragma unroll
    for (int kk = 0; kk < 4; ++kk) {
      float4 w = *(const float4*)&Wsh[(k + kk) * NCOLP + c0];
#pragma unroll
      for (int i = 0; i < 4; ++i) {
        float av = (&a[i].x)[kk];
        acc[i][0] += av * w.x; acc[i][1] += av * w.y;
        acc[i][2] += av * w.z; acc[i][3] += av * w.w;
      }
    }
  }

#pragma unroll
  for (int i = 0; i < 4; ++i) {
    int row = r0 + rl + i;
    if (row < n && (NOUT == NCOLP || c0 < NOUT)) {
      float di = dinv[row];
      uint2 p;
      p.x = f2bf(acc[i][0] * di) | (f2bf(acc[i][1] * di) << 16);
      p.y = f2bf(acc[i][2] * di) | (f2bf(acc[i][3] * di) << 16);
      *(uint2*)&Hout[(size_t)row * NOUT + c0] = p;   // 8B-aligned: NOUT,c0 even
    }
  }
}

// ---------------------------------------------------------------------------
// Pull aggregation over bf16 h', fp32 accumulate, 16 gathers in flight
// (avg degree ~16 -> one batch covers most rows; limiter is lines-in-flight).
// ---------------------------------------------------------------------------
__global__ __launch_bounds__(256) void pull128(
    const unsigned short* __restrict__ H, const int* __restrict__ rowptr,
    const int* __restrict__ adj, const float* __restrict__ dinv,
    const float* __restrict__ bias, float* __restrict__ out, int n)
{
  int wid = (blockIdx.x * 256 + threadIdx.x) >> 6;
  int lane = threadIdx.x & 63;
  if (wid >= n) return;
  int beg = rowptr[wid], end = rowptr[wid + 1];
  const unsigned* Hu = (const unsigned*)H;           // 64 uints per row
  unsigned su = Hu[(size_t)wid * 64 + lane];         // self-loop term
  float2 acc[8];
  acc[0] = make_float2(bf_lo(su), bf_hi(su));
#pragma unroll
  for (int k = 1; k < 8; ++k) acc[k] = make_float2(0.f, 0.f);

  int last = end - 1;
  for (int j = beg; j < end; j += 16) {
    int idx[16];
#pragma unroll
    for (int k = 0; k < 16; ++k) idx[k] = adj[min(j + k, last)];
    unsigned u[16];
#pragma unroll
    for (int k = 0; k < 16; ++k)
      u[k] = Hu[(size_t)idx[k] * 64 + lane];
#pragma unroll
    for (int k = 0; k < 16; ++k) {
      if (j + k <= last) {
        acc[k & 7].x += bf_lo(u[k]);
        acc[k & 7].y += bf_hi(u[k]);
      }
    }
  }

  float2 s0 = make_float2((acc[0].x + acc[1].x) + (acc[2].x + acc[3].x),
                          (acc[0].y + acc[1].y) + (acc[2].y + acc[3].y));
  float2 s1 = make_float2((acc[4].x + acc[5].x) + (acc[6].x + acc[7].x),
                          (acc[4].y + acc[5].y) + (acc[6].y + acc[7].y));
  int c = lane * 2;
  float di = dinv[wid];
  float2 o;
  o.x = (s0.x + s1.x) * di + bias[c];
  o.y = (s0.y + s1.y) * di + bias[c + 1];
  *(float2*)&out[(size_t)wid * 128 + c] = o;
}

__global__ __launch_bounds__(256) void pull40(
    const unsigned short* __restrict__ H, const int* __restrict__ rowptr,
    const int* __restrict__ adj, const float* __restrict__ dinv,
    const float* __restrict__ bias, float* __restrict__ out, int n)
{
  int wid = (blockIdx.x * 256 + threadIdx.x) >> 6;
  int lane = threadIdx.x & 63;
  if (wid >= n) return;
  int beg = rowptr[wid], end = rowptr[wid + 1];
  bool act = lane < 40;
  float acc[8];
  acc[0] = act ? __uint_as_float((unsigned)H[(size_t)wid * 40 + lane] << 16) : 0.f;
#pragma unroll
  for (int k = 1; k < 8; ++k) acc[k] = 0.f;

  int last = end - 1;
  for (int j = beg; j < end; j += 16) {
    int idx[16];
#pragma unroll
    for (int k = 0; k < 16; ++k) idx[k] = adj[min(j + k, last)];
    float v[16];
#pragma unroll
    for (int k = 0; k < 16; ++k)
      v[k] = act ? __uint_as_float((unsigned)H[(size_t)idx[k] * 40 + lane] << 16) : 0.f;
#pragma unroll
    for (int k = 0; k < 16; ++k) {
      if (j + k <= last) acc[k & 7] += v[k];
    }
  }

  float s = ((acc[0] + acc[1]) + (acc[2] + acc[3])) +
            ((acc[4] + acc[5]) + (acc[6] + acc[7]));
  if (act) out[(size_t)wid * 40 + lane] = s * dinv[wid] + bias[lane];
}

// ---------------------------------------------------------------------------
extern "C" void kernel_launch(void* const* d_in, const int* in_sizes, int n_in,
                              void* d_out, int out_size, void* d_ws, size_t ws_size,
                              hipStream_t stream) {
  const float* x  = (const float*)d_in[0];
  const int*   ei = (const int*)d_in[1];
  const float* W1 = (const float*)d_in[2];
  const float* b1 = (const float*)d_in[3];
  const float* W2 = (const float*)d_in[4];
  const float* b2 = (const float*)d_in[5];
  const int n = in_sizes[0] / 128;
  const int e = in_sizes[1] / 2;
  const int* src = ei;
  const int* dst = ei + e;

  // kd1, kd2 = jax.random.split(jax.random.key(42))  [fold-like split]
  unsigned kd1a = 0u, kd1b = 0u; tf2x32(0u, 42u, kd1a, kd1b);  // ctr (0,0)
  unsigned kd2a = 0u, kd2b = 1u; tf2x32(0u, 42u, kd2a, kd2b);  // ctr (0,1)

  char* wsp = (char*)d_ws;
  size_t off = 0;
  auto take = [&](size_t bytes) -> char* {
    char* p = wsp + off;
    off = (off + bytes + 255) & ~(size_t)255;
    return p;
  };
  int*   cnt    = (int*)take((size_t)n * 4);
  int*   excl   = (int*)take((size_t)n * 4);
  int*   bsum   = (int*)take(1024);
  int*   rowptr = (int*)take((size_t)(n + 1) * 4);
  float* dinv   = (float*)take((size_t)n * 4);
  int*   adj    = (int*)take((size_t)e * 4);
  unsigned short* Hb = (unsigned short*)take((size_t)n * 128 * 2);  // bf16 h'
  float* Sbuf   = (float*)take((size_t)n * 128 * 4);
  size_t base_off = off;
  int*   rank   = (int*)take((size_t)e * 4);        // fast path only
  bool use_rank = (off <= ws_size);
  int*   cursor = use_rank ? nullptr : (int*)(wsp + base_off);  // n*4 fits (< e*4)
  (void)n_in; (void)out_size;

  hipMemsetAsync(cnt, 0, (size_t)n * 4, stream);
  if (use_rank) {
    count_rank<<<(e / 4 + 256) / 256, 256, 0, stream>>>(dst, cnt, rank, e);
  } else {
    count_rank<<<(e / 4 + 256) / 256, 256, 0, stream>>>(dst, cnt, cursor, e); // rank discarded later
  }
  int nblk = (n + 511) / 512;
  scan_local<<<nblk, 512, 0, stream>>>(cnt, excl, bsum, dinv, n);
  scan_bsum<<<1, 256, 0, stream>>>(bsum, nblk);
  scan_final<<<(n + 256) / 256, 256, 0, stream>>>(excl, bsum, rowptr, cursor,
                                                  n, e, use_rank ? 0 : 1);
  if (use_rank) {
    fill_csr<<<(e / 8 + 256) / 256, 256, 0, stream>>>(src, dst, rank, rowptr, adj, e);
  } else {
    fill_adj_cursor<<<(e / 4 + 256) / 256, 256, 0, stream>>>(src, dst, cursor, adj, e);
  }

  // layer 1: h1' = dinv * (relu(drop_kd1(x)) @ W1)  [bf16]  ->  s1 = pull + b1
  gemm_drop<32, 128, 128, 128><<<(n + 31) / 32, 256, 0, stream>>>(
      x, W1, dinv, Hb, n, kd1a, kd1b);
  pull128<<<(n + 3) / 4, 256, 0, stream>>>(Hb, rowptr, adj, dinv, b1, Sbuf, n);

  // layer 2: h2' = dinv * (relu(drop_kd2(s1)) @ W2) [bf16]  -> out = pull + b2
  gemm_drop<64, 132, 64, 40><<<(n + 63) / 64, 256, 0, stream>>>(
      Sbuf, W2, dinv, Hb, n, kd2a, kd2b);
  pull40<<<(n + 3) / 4, 256, 0, stream>>>(Hb, rowptr, adj, dinv, b2,
                                          (float*)d_out, n);
}

// Round 9
// 458.311 us; speedup vs baseline: 1.2241x; 1.2241x over previous
//
#include <hip/hip_runtime.h>
#include <stdint.h>

// ---------------------------------------------------------------------------
// Threefry-2x32 (20 rounds) — exact JAX semantics.
// ---------------------------------------------------------------------------
__host__ __device__ inline void tf2x32(unsigned k0, unsigned k1,
                                       unsigned& x0, unsigned& x1) {
  unsigned k2 = k0 ^ k1 ^ 0x1BD11BDAu;
  x0 += k0; x1 += k1;
#define TFR(r) { x0 += x1; x1 = (x1 << (r)) | (x1 >> (32 - (r))); x1 ^= x0; }
  TFR(13) TFR(15) TFR(26) TFR(6)
  x0 += k1; x1 += k2 + 1u;
  TFR(17) TFR(29) TFR(16) TFR(24)
  x0 += k2; x1 += k0 + 2u;
  TFR(13) TFR(15) TFR(26) TFR(6)
  x0 += k0; x1 += k1 + 3u;
  TFR(17) TFR(29) TFR(16) TFR(24)
  x0 += k1; x1 += k2 + 4u;
  TFR(13) TFR(15) TFR(26) TFR(6)
  x0 += k2; x1 += k0 + 5u;
#undef TFR
}

__device__ __forceinline__ float drop_scale(unsigned k0, unsigned k1, unsigned f) {
  unsigned a = 0u, b = f;
  tf2x32(k0, k1, a, b);
  unsigned bits = a ^ b;
  float u = __uint_as_float((bits >> 9) | 0x3f800000u) - 1.0f;
  return (u < 0.8f) ? 1.25f : 0.0f;
}

// fp32 -> bf16 (RNE) and unpack helpers
__device__ __forceinline__ unsigned f2bf(float x) {
  unsigned u = __float_as_uint(x);
  return (u + 0x7fffu + ((u >> 16) & 1u)) >> 16;
}
__device__ __forceinline__ float bf_lo(unsigned u) { return __uint_as_float(u << 16); }
__device__ __forceinline__ float bf_hi(unsigned u) { return __uint_as_float(u & 0xffff0000u); }

// ---------------------------------------------------------------------------
// CSR build: count+rank -> scan -> atomic-free fill
// ---------------------------------------------------------------------------
__global__ __launch_bounds__(256) void count_rank(
    const int* __restrict__ dst, int* __restrict__ cnt,
    int* __restrict__ rank, int e) {
  int i0 = (blockIdx.x * 256 + threadIdx.x) * 4;
  if (i0 + 3 < e) {
    int4 d4 = *(const int4*)&dst[i0];
    int4 r4;
    r4.x = atomicAdd(&cnt[d4.x], 1);
    r4.y = atomicAdd(&cnt[d4.y], 1);
    r4.z = atomicAdd(&cnt[d4.z], 1);
    r4.w = atomicAdd(&cnt[d4.w], 1);
    *(int4*)&rank[i0] = r4;
  } else {
    for (int i = i0; i < e; ++i)
      rank[i] = atomicAdd(&cnt[dst[i]], 1);
  }
}

__global__ __launch_bounds__(256) void fill_adj_cursor(
    const int* __restrict__ src, const int* __restrict__ dst,
    int* __restrict__ cursor, int* __restrict__ adj, int e) {
  int i0 = (blockIdx.x * 256 + threadIdx.x) * 4;
  for (int i = i0; i < min(i0 + 4, e); ++i) {
    int d = dst[i];
    int p = atomicAdd(&cursor[d], 1);
    adj[p] = src[i];
  }
}

__global__ void scan_local(const int* __restrict__ cnt, int* __restrict__ excl,
                           int* __restrict__ bsum, float* __restrict__ dinv, int n) {
  __shared__ int sh[512];
  int i = blockIdx.x * 512 + threadIdx.x;
  int v = (i < n) ? cnt[i] : 0;
  if (i < n) dinv[i] = 1.0f / sqrtf((float)v + 1.0f);
  sh[threadIdx.x] = v;
  __syncthreads();
  for (int d = 1; d < 512; d <<= 1) {
    int t = (threadIdx.x >= d) ? sh[threadIdx.x - d] : 0;
    __syncthreads();
    sh[threadIdx.x] += t;
    __syncthreads();
  }
  if (i < n) excl[i] = sh[threadIdx.x] - v;
  if (threadIdx.x == 511) bsum[blockIdx.x] = sh[511];
}

__global__ void scan_bsum(int* __restrict__ bsum, int nb) {
  __shared__ int sh[256];
  int tid = threadIdx.x;
  int v = (tid < nb) ? bsum[tid] : 0;
  sh[tid] = v;
  __syncthreads();
  for (int d = 1; d < 256; d <<= 1) {
    int t = (tid >= d) ? sh[tid - d] : 0;
    __syncthreads();
    sh[tid] += t;
    __syncthreads();
  }
  if (tid < nb) bsum[tid] = sh[tid] - v;
}

__global__ void scan_final(const int* __restrict__ excl, const int* __restrict__ bsum,
                           int* __restrict__ rowptr, int* __restrict__ cursor,
                           int n, int e, int write_cursor) {
  int i = blockIdx.x * blockDim.x + threadIdx.x;
  if (i < n) {
    int r = excl[i] + bsum[i >> 9];
    rowptr[i] = r;
    if (write_cursor) cursor[i] = r;
  }
  if (i == n) rowptr[n] = e;
}

__global__ __launch_bounds__(256) void fill_csr(
    const int* __restrict__ src, const int* __restrict__ dst,
    const int* __restrict__ rank, const int* __restrict__ rowptr,
    int* __restrict__ adj, int e) {
  int i0 = (blockIdx.x * 256 + threadIdx.x) * 8;
  if (i0 + 7 < e) {
    int4 d0 = *(const int4*)&dst[i0];
    int4 d1 = *(const int4*)&dst[i0 + 4];
    int4 r0 = *(const int4*)&rank[i0];
    int4 r1 = *(const int4*)&rank[i0 + 4];
    int4 s0 = *(const int4*)&src[i0];
    int4 s1 = *(const int4*)&src[i0 + 4];
    int p0 = rowptr[d0.x] + r0.x;
    int p1 = rowptr[d0.y] + r0.y;
    int p2 = rowptr[d0.z] + r0.z;
    int p3 = rowptr[d0.w] + r0.w;
    int p4 = rowptr[d1.x] + r1.x;
    int p5 = rowptr[d1.y] + r1.y;
    int p6 = rowptr[d1.z] + r1.z;
    int p7 = rowptr[d1.w] + r1.w;
    adj[p0] = s0.x; adj[p1] = s0.y; adj[p2] = s0.z; adj[p3] = s0.w;
    adj[p4] = s1.x; adj[p5] = s1.y; adj[p6] = s1.z; adj[p7] = s1.w;
  } else {
    for (int i = i0; i < e; ++i)
      adj[rowptr[dst[i]] + rank[i]] = src[i];
  }
}

// ---------------------------------------------------------------------------
// Layer-1 GEMM, K-chunked W staging (32KB LDS total -> ~5 blocks/CU):
//   h1'[r][c] = dinv[r] * sum_k relu(drop_kd1(x[r][k])) * W1[k][c], bf16 out.
// ---------------------------------------------------------------------------
__global__ __launch_bounds__(256) void gemm_l1(
    const float* __restrict__ A, const float* __restrict__ W,
    const float* __restrict__ dinv, unsigned short* __restrict__ Hout,
    int n, unsigned kd0, unsigned kd1)
{
  __shared__ float Ash[32 * 128];   // 16 KB
  __shared__ float Wsh[32 * 128];   // 16 KB (one 32-row K-chunk of W)
  const int tid = threadIdx.x;
  const int r0 = blockIdx.x * 32;
  const float4* W4 = (const float4*)W;
  float4* Ws4 = (float4*)Wsh;

  // stage A with fused dropout+relu (whole K=128 per row)
  for (int i4 = tid; i4 < 32 * 32; i4 += 256) {
    int rr = i4 >> 5;
    int k4 = (i4 & 31) << 2;
    int row = r0 + rr;
    float4 v = make_float4(0.f, 0.f, 0.f, 0.f);
    if (row < n) {
      v = *(const float4*)&A[(size_t)row * 128 + k4];
      unsigned fb = (unsigned)row * 128u + (unsigned)k4;
      float* pv = &v.x;
#pragma unroll
      for (int j = 0; j < 4; ++j)
        pv[j] = fmaxf(pv[j], 0.0f) * drop_scale(kd0, kd1, fb + j);
    }
    *(float4*)&Ash[rr * 128 + k4] = v;
  }
  // stage W chunk 0
  for (int i = tid; i < 1024; i += 256) Ws4[i] = W4[i];
  __syncthreads();

  const int tx = tid & 31, ty = tid >> 5;
  const int c0 = tx * 4;
  const int rl = ty * 4;
  float acc[4][4] = {};
  for (int kb = 0; kb < 4; ++kb) {
    if (kb) {
      __syncthreads();
      for (int i = tid; i < 1024; i += 256) Ws4[i] = W4[kb * 1024 + i];
      __syncthreads();
    }
    const int kbase = kb * 32;
    for (int k = 0; k < 32; k += 4) {
      float4 a[4];
#pragma unroll
      for (int i = 0; i < 4; ++i)
        a[i] = *(const float4*)&Ash[(rl + i) * 128 + kbase + k];
#pragma unroll
      for (int kk = 0; kk < 4; ++kk) {
        float4 w = *(const float4*)&Wsh[(k + kk) * 128 + c0];
#pragma unroll
        for (int i = 0; i < 4; ++i) {
          float av = (&a[i].x)[kk];
          acc[i][0] += av * w.x; acc[i][1] += av * w.y;
          acc[i][2] += av * w.z; acc[i][3] += av * w.w;
        }
      }
    }
  }

#pragma unroll
  for (int i = 0; i < 4; ++i) {
    int row = r0 + rl + i;
    if (row < n) {
      float di = dinv[row];
      uint2 p;
      p.x = f2bf(acc[i][0] * di) | (f2bf(acc[i][1] * di) << 16);
      p.y = f2bf(acc[i][2] * di) | (f2bf(acc[i][3] * di) << 16);
      *(uint2*)&Hout[(size_t)row * 128 + c0] = p;
    }
  }
}

// ---------------------------------------------------------------------------
// Pull over bf16 rows, fp32 accumulate, 8 gathers in flight.
// FUSE_F=true:  Out = bf16( di * relu( (acc*di + b1) * drop_kd2 ) )   [F pass]
// FUSE_F=false: Out = bf16( di * acc )                                 [G pass]
// ---------------------------------------------------------------------------
template<bool FUSE_F>
__global__ __launch_bounds__(256) void pull128k(
    const unsigned short* __restrict__ H, const int* __restrict__ rowptr,
    const int* __restrict__ adj, const float* __restrict__ dinv,
    const float* __restrict__ bias, unsigned short* __restrict__ Out,
    int n, unsigned k0, unsigned k1)
{
  int wid = (blockIdx.x * 256 + threadIdx.x) >> 6;
  int lane = threadIdx.x & 63;
  if (wid >= n) return;
  int beg = rowptr[wid], end = rowptr[wid + 1];
  const unsigned* Hu = (const unsigned*)H;           // 64 uints per row
  unsigned su = Hu[(size_t)wid * 64 + lane];         // self-loop term
  float2 acc[8];
  acc[0] = make_float2(bf_lo(su), bf_hi(su));
#pragma unroll
  for (int k = 1; k < 8; ++k) acc[k] = make_float2(0.f, 0.f);

  int last = end - 1;
  for (int j = beg; j < end; j += 8) {
    int idx[8];
#pragma unroll
    for (int k = 0; k < 8; ++k) idx[k] = adj[min(j + k, last)];
    unsigned u[8];
#pragma unroll
    for (int k = 0; k < 8; ++k)
      u[k] = Hu[(size_t)idx[k] * 64 + lane];
#pragma unroll
    for (int k = 0; k < 8; ++k) {
      if (j + k <= last) { acc[k].x += bf_lo(u[k]); acc[k].y += bf_hi(u[k]); }
    }
  }

  float sx = ((acc[0].x + acc[1].x) + (acc[2].x + acc[3].x)) +
             ((acc[4].x + acc[5].x) + (acc[6].x + acc[7].x));
  float sy = ((acc[0].y + acc[1].y) + (acc[2].y + acc[3].y)) +
             ((acc[4].y + acc[5].y) + (acc[6].y + acc[7].y));
  float di = dinv[wid];
  unsigned c = (unsigned)lane * 2u;
  float o0, o1;
  if (FUSE_F) {
    float s1a = sx * di + bias[c];
    float s1b = sy * di + bias[c + 1];
    unsigned fb = (unsigned)wid * 128u + c;
    o0 = di * fmaxf(s1a * drop_scale(k0, k1, fb), 0.0f);
    o1 = di * fmaxf(s1b * drop_scale(k0, k1, fb + 1u), 0.0f);
  } else {
    o0 = sx * di;
    o1 = sy * di;
  }
  ((unsigned*)Out)[(size_t)wid * 64 + lane] = f2bf(o0) | (f2bf(o1) << 16);
}

// ---------------------------------------------------------------------------
// Final dense GEMM: out[n][40] = G[n][128](bf16) @ W2[128][40] + b2, fp32 out.
// Ash 32KB + Wsh 8KB -> 4 blocks/CU.
// ---------------------------------------------------------------------------
__global__ __launch_bounds__(256) void gemm_out(
    const unsigned short* __restrict__ G, const float* __restrict__ W2,
    const float* __restrict__ b2, float* __restrict__ out, int n)
{
  __shared__ float Ash[64 * 128];   // 32 KB
  __shared__ float Wsh[32 * 64];    // 8 KB (one K-chunk, cols padded to 64)
  const int tid = threadIdx.x;
  const int r0 = blockIdx.x * 64;
  const uint2* G2 = (const uint2*)G;                 // 32 uint2 per row

  for (int i = tid; i < 64 * 32; i += 256) {
    int rr = i >> 5, q = i & 31;
    int row = r0 + rr;
    uint2 g = make_uint2(0u, 0u);
    if (row < n) g = G2[(size_t)row * 32 + q];
    float* d = &Ash[rr * 128 + q * 4];
    d[0] = bf_lo(g.x); d[1] = bf_hi(g.x);
    d[2] = bf_lo(g.y); d[3] = bf_hi(g.y);
  }

  const int tx = tid & 15, ty = tid >> 4;
  const int c0 = tx * 4;
  const int rl = ty * 4;
  float acc[4][4] = {};
  for (int kb = 0; kb < 4; ++kb) {
    __syncthreads();    // Ash ready (kb=0) / Wsh consumed (kb>0)
    for (int i = tid; i < 2048; i += 256) {
      int r = i >> 6, c = i & 63;
      Wsh[i] = (c < 40) ? W2[(kb * 32 + r) * 40 + c] : 0.0f;
    }
    __syncthreads();
    const int kbase = kb * 32;
    for (int k = 0; k < 32; k += 4) {
      float4 a[4];
#pragma unroll
      for (int i = 0; i < 4; ++i)
        a[i] = *(const float4*)&Ash[(rl + i) * 128 + kbase + k];
#pragma unroll
      for (int kk = 0; kk < 4; ++kk) {
        float4 w = *(const float4*)&Wsh[(k + kk) * 64 + c0];
#pragma unroll
        for (int i = 0; i < 4; ++i) {
          float av = (&a[i].x)[kk];
          acc[i][0] += av * w.x; acc[i][1] += av * w.y;
          acc[i][2] += av * w.z; acc[i][3] += av * w.w;
        }
      }
    }
  }

  if (c0 < 40) {
#pragma unroll
    for (int i = 0; i < 4; ++i) {
      int row = r0 + rl + i;
      if (row < n) {
        float4 o = make_float4(acc[i][0] + b2[c0],     acc[i][1] + b2[c0 + 1],
                               acc[i][2] + b2[c0 + 2], acc[i][3] + b2[c0 + 3]);
        *(float4*)&out[(size_t)row * 40 + c0] = o;     // 160B rows: 16B aligned
      }
    }
  }
}

// ---------------------------------------------------------------------------
extern "C" void kernel_launch(void* const* d_in, const int* in_sizes, int n_in,
                              void* d_out, int out_size, void* d_ws, size_t ws_size,
                              hipStream_t stream) {
  const float* x  = (const float*)d_in[0];
  const int*   ei = (const int*)d_in[1];
  const float* W1 = (const float*)d_in[2];
  const float* b1 = (const float*)d_in[3];
  const float* W2 = (const float*)d_in[4];
  const float* b2 = (const float*)d_in[5];
  const int n = in_sizes[0] / 128;
  const int e = in_sizes[1] / 2;
  const int* src = ei;
  const int* dst = ei + e;

  // kd1, kd2 = jax.random.split(jax.random.key(42))  [fold-like split]
  unsigned kd1a = 0u, kd1b = 0u; tf2x32(0u, 42u, kd1a, kd1b);  // ctr (0,0)
  unsigned kd2a = 0u, kd2b = 1u; tf2x32(0u, 42u, kd2a, kd2b);  // ctr (0,1)

  char* wsp = (char*)d_ws;
  size_t off = 0;
  auto take = [&](size_t bytes) -> char* {
    char* p = wsp + off;
    off = (off + bytes + 255) & ~(size_t)255;
    return p;
  };
  int*   cnt    = (int*)take((size_t)n * 4);
  int*   excl   = (int*)take((size_t)n * 4);
  int*   bsum   = (int*)take(1024);
  int*   rowptr = (int*)take((size_t)(n + 1) * 4);
  float* dinv   = (float*)take((size_t)n * 4);
  int*   adj    = (int*)take((size_t)e * 4);
  unsigned short* Hb = (unsigned short*)take((size_t)n * 128 * 2);  // h1' / G
  unsigned short* Fb = (unsigned short*)take((size_t)n * 128 * 2);  // F
  size_t base_off = off;
  int*   rank   = (int*)take((size_t)e * 4);        // fast path only
  bool use_rank = (off <= ws_size);
  int*   cursor = use_rank ? nullptr : (int*)(wsp + base_off);
  (void)n_in; (void)out_size;

  hipMemsetAsync(cnt, 0, (size_t)n * 4, stream);
  if (use_rank) {
    count_rank<<<(e / 4 + 256) / 256, 256, 0, stream>>>(dst, cnt, rank, e);
  } else {
    count_rank<<<(e / 4 + 256) / 256, 256, 0, stream>>>(dst, cnt, cursor, e);
  }
  int nblk = (n + 511) / 512;
  scan_local<<<nblk, 512, 0, stream>>>(cnt, excl, bsum, dinv, n);
  scan_bsum<<<1, 256, 0, stream>>>(bsum, nblk);
  scan_final<<<(n + 256) / 256, 256, 0, stream>>>(excl, bsum, rowptr, cursor,
                                                  n, e, use_rank ? 0 : 1);
  if (use_rank) {
    fill_csr<<<(e / 8 + 256) / 256, 256, 0, stream>>>(src, dst, rank, rowptr, adj, e);
  } else {
    fill_adj_cursor<<<(e / 4 + 256) / 256, 256, 0, stream>>>(src, dst, cursor, adj, e);
  }

  // layer 1: h1' = bf16(dinv * (relu(drop_kd1(x)) @ W1))
  gemm_l1<<<(n + 31) / 32, 256, 0, stream>>>(x, W1, dinv, Hb, n, kd1a, kd1b);

  // F = bf16(dinv * relu(drop_kd2(pull(h1') + b1)))
  pull128k<true><<<(n + 3) / 4, 256, 0, stream>>>(Hb, rowptr, adj, dinv, b1,
                                                  Fb, n, kd2a, kd2b);

  // G = bf16(dinv * (pull(F)))   [aggregation commutes with @W2]
  pull128k<false><<<(n + 3) / 4, 256, 0, stream>>>(Fb, rowptr, adj, dinv, b1,
                                                   Hb, n, 0u, 0u);

  // out = G @ W2 + b2
  gemm_out<<<(n + 63) / 64, 256, 0, stream>>>(Hb, W2, b2, (float*)d_out, n);
}

// Round 10
// 438.132 us; speedup vs baseline: 1.2805x; 1.0461x over previous
//
#include <hip/hip_runtime.h>
#include <stdint.h>

typedef __attribute__((ext_vector_type(8))) short bf16x8;
typedef __attribute__((ext_vector_type(4))) float f32x4;

// ---------------------------------------------------------------------------
// Threefry-2x32 (20 rounds) — exact JAX semantics.
// ---------------------------------------------------------------------------
__host__ __device__ inline void tf2x32(unsigned k0, unsigned k1,
                                       unsigned& x0, unsigned& x1) {
  unsigned k2 = k0 ^ k1 ^ 0x1BD11BDAu;
  x0 += k0; x1 += k1;
#define TFR(r) { x0 += x1; x1 = (x1 << (r)) | (x1 >> (32 - (r))); x1 ^= x0; }
  TFR(13) TFR(15) TFR(26) TFR(6)
  x0 += k1; x1 += k2 + 1u;
  TFR(17) TFR(29) TFR(16) TFR(24)
  x0 += k2; x1 += k0 + 2u;
  TFR(13) TFR(15) TFR(26) TFR(6)
  x0 += k0; x1 += k1 + 3u;
  TFR(17) TFR(29) TFR(16) TFR(24)
  x0 += k1; x1 += k2 + 4u;
  TFR(13) TFR(15) TFR(26) TFR(6)
  x0 += k2; x1 += k0 + 5u;
#undef TFR
}

__device__ __forceinline__ float drop_scale(unsigned k0, unsigned k1, unsigned f) {
  unsigned a = 0u, b = f;
  tf2x32(k0, k1, a, b);
  unsigned bits = a ^ b;
  float u = __uint_as_float((bits >> 9) | 0x3f800000u) - 1.0f;
  return (u < 0.8f) ? 1.25f : 0.0f;
}

// fp32 -> bf16 (RNE) and unpack helpers
__device__ __forceinline__ unsigned f2bf(float x) {
  unsigned u = __float_as_uint(x);
  return (u + 0x7fffu + ((u >> 16) & 1u)) >> 16;
}
__device__ __forceinline__ float bf_lo(unsigned u) { return __uint_as_float(u << 16); }
__device__ __forceinline__ float bf_hi(unsigned u) { return __uint_as_float(u & 0xffff0000u); }

// ---------------------------------------------------------------------------
// CSR build: count+rank -> scan -> atomic-free fill
// ---------------------------------------------------------------------------
__global__ __launch_bounds__(256) void count_rank(
    const int* __restrict__ dst, int* __restrict__ cnt,
    int* __restrict__ rank, int e) {
  int i0 = (blockIdx.x * 256 + threadIdx.x) * 4;
  if (i0 + 3 < e) {
    int4 d4 = *(const int4*)&dst[i0];
    int4 r4;
    r4.x = atomicAdd(&cnt[d4.x], 1);
    r4.y = atomicAdd(&cnt[d4.y], 1);
    r4.z = atomicAdd(&cnt[d4.z], 1);
    r4.w = atomicAdd(&cnt[d4.w], 1);
    *(int4*)&rank[i0] = r4;
  } else {
    for (int i = i0; i < e; ++i)
      rank[i] = atomicAdd(&cnt[dst[i]], 1);
  }
}

__global__ __launch_bounds__(256) void fill_adj_cursor(
    const int* __restrict__ src, const int* __restrict__ dst,
    int* __restrict__ cursor, int* __restrict__ adj, int e) {
  int i0 = (blockIdx.x * 256 + threadIdx.x) * 4;
  for (int i = i0; i < min(i0 + 4, e); ++i) {
    int d = dst[i];
    int p = atomicAdd(&cursor[d], 1);
    adj[p] = src[i];
  }
}

__global__ void scan_local(const int* __restrict__ cnt, int* __restrict__ excl,
                           int* __restrict__ bsum, float* __restrict__ dinv, int n) {
  __shared__ int sh[512];
  int i = blockIdx.x * 512 + threadIdx.x;
  int v = (i < n) ? cnt[i] : 0;
  if (i < n) dinv[i] = 1.0f / sqrtf((float)v + 1.0f);
  sh[threadIdx.x] = v;
  __syncthreads();
  for (int d = 1; d < 512; d <<= 1) {
    int t = (threadIdx.x >= d) ? sh[threadIdx.x - d] : 0;
    __syncthreads();
    sh[threadIdx.x] += t;
    __syncthreads();
  }
  if (i < n) excl[i] = sh[threadIdx.x] - v;
  if (threadIdx.x == 511) bsum[blockIdx.x] = sh[511];
}

__global__ void scan_bsum(int* __restrict__ bsum, int nb) {
  __shared__ int sh[256];
  int tid = threadIdx.x;
  int v = (tid < nb) ? bsum[tid] : 0;
  sh[tid] = v;
  __syncthreads();
  for (int d = 1; d < 256; d <<= 1) {
    int t = (tid >= d) ? sh[tid - d] : 0;
    __syncthreads();
    sh[tid] += t;
    __syncthreads();
  }
  if (tid < nb) bsum[tid] = sh[tid] - v;
}

__global__ void scan_final(const int* __restrict__ excl, const int* __restrict__ bsum,
                           int* __restrict__ rowptr, int* __restrict__ cursor,
                           int n, int e, int write_cursor) {
  int i = blockIdx.x * blockDim.x + threadIdx.x;
  if (i < n) {
    int r = excl[i] + bsum[i >> 9];
    rowptr[i] = r;
    if (write_cursor) cursor[i] = r;
  }
  if (i == n) rowptr[n] = e;
}

__global__ __launch_bounds__(256) void fill_csr(
    const int* __restrict__ src, const int* __restrict__ dst,
    const int* __restrict__ rank, const int* __restrict__ rowptr,
    int* __restrict__ adj, int e) {
  int i0 = (blockIdx.x * 256 + threadIdx.x) * 8;
  if (i0 + 7 < e) {
    int4 d0 = *(const int4*)&dst[i0];
    int4 d1 = *(const int4*)&dst[i0 + 4];
    int4 r0 = *(const int4*)&rank[i0];
    int4 r1 = *(const int4*)&rank[i0 + 4];
    int4 s0 = *(const int4*)&src[i0];
    int4 s1 = *(const int4*)&src[i0 + 4];
    int p0 = rowptr[d0.x] + r0.x;
    int p1 = rowptr[d0.y] + r0.y;
    int p2 = rowptr[d0.z] + r0.z;
    int p3 = rowptr[d0.w] + r0.w;
    int p4 = rowptr[d1.x] + r1.x;
    int p5 = rowptr[d1.y] + r1.y;
    int p6 = rowptr[d1.z] + r1.z;
    int p7 = rowptr[d1.w] + r1.w;
    adj[p0] = s0.x; adj[p1] = s0.y; adj[p2] = s0.z; adj[p3] = s0.w;
    adj[p4] = s1.x; adj[p5] = s1.y; adj[p6] = s1.z; adj[p7] = s1.w;
  } else {
    for (int i = i0; i < e; ++i)
      adj[rowptr[dst[i]] + rank[i]] = src[i];
  }
}

// ---------------------------------------------------------------------------
// Prep: W1 (fp32 [k][c]) -> Wt (bf16 [c][k]) for MFMA B-operand staging.
// ---------------------------------------------------------------------------
__global__ __launch_bounds__(256) void w1t_bf16(
    const float* __restrict__ W, unsigned short* __restrict__ Wt) {
  int i = blockIdx.x * 256 + threadIdx.x;       // 16384 elements
  int k = i >> 7, c = i & 127;
  Wt[c * 128 + k] = (unsigned short)f2bf(W[i]);
}

// ---------------------------------------------------------------------------
// Layer-1 GEMM via bf16 MFMA (16x16x32):
//   h1'[r][c] = bf16( dinv[r] * sum_k relu(drop_kd1(x[r][k])) * W1[k][c] )
// 64 rows/block, 4 waves (16 rows each), Ash 16KB + Wsh 32KB (swizzled).
// Fragment layouts (m89-verified D; documented A/B):
//   A: lane l -> row=l&15, k=(l>>4)*8+j    B: lane l -> col=l&15, same k
//   D: lane l, reg r -> col=l&15, row=(l>>4)*4+r
// LDS swizzle: 16B-slot index ch -> ch ^ (row&7)  (both write and read sides).
// ---------------------------------------------------------------------------
__global__ __launch_bounds__(256) void gemm_l1_mfma(
    const float* __restrict__ A, const unsigned short* __restrict__ Wt,
    const float* __restrict__ dinv, unsigned short* __restrict__ Hout,
    int n, unsigned kd0, unsigned kd1)
{
  __shared__ unsigned short Ash[64 * 128];    // 16 KB
  __shared__ unsigned short Wsh[128 * 128];   // 32 KB
  const int tid = threadIdx.x;
  const int r0 = blockIdx.x * 64;

  // stage Wt -> Wsh (swizzled), 2048 x 16B chunks
  {
    const uint4* Wg = (const uint4*)Wt;
    uint4* Ws = (uint4*)Wsh;
    for (int j = tid; j < 2048; j += 256) {
      int row = j >> 4, ch = j & 15;
      Ws[row * 16 + (ch ^ (row & 7))] = Wg[j];
    }
  }

  // stage A -> Ash (dropout+relu+cvt, swizzled), 1024 x 16B chunks (8 bf16)
  {
    uint4* As = (uint4*)Ash;
    for (int j = tid; j < 1024; j += 256) {
      int row = j >> 4, ch = j & 15;
      int grow = r0 + row;
      uint4 pk = make_uint4(0u, 0u, 0u, 0u);
      if (grow < n) {
        const float4* p = (const float4*)&A[(size_t)grow * 128 + ch * 8];
        float4 f0 = p[0], f1 = p[1];
        unsigned fb = (unsigned)grow * 128u + (unsigned)(ch * 8);
        float a0 = fmaxf(f0.x, 0.f) * drop_scale(kd0, kd1, fb + 0u);
        float a1 = fmaxf(f0.y, 0.f) * drop_scale(kd0, kd1, fb + 1u);
        float a2 = fmaxf(f0.z, 0.f) * drop_scale(kd0, kd1, fb + 2u);
        float a3 = fmaxf(f0.w, 0.f) * drop_scale(kd0, kd1, fb + 3u);
        float a4 = fmaxf(f1.x, 0.f) * drop_scale(kd0, kd1, fb + 4u);
        float a5 = fmaxf(f1.y, 0.f) * drop_scale(kd0, kd1, fb + 5u);
        float a6 = fmaxf(f1.z, 0.f) * drop_scale(kd0, kd1, fb + 6u);
        float a7 = fmaxf(f1.w, 0.f) * drop_scale(kd0, kd1, fb + 7u);
        pk.x = f2bf(a0) | (f2bf(a1) << 16);
        pk.y = f2bf(a2) | (f2bf(a3) << 16);
        pk.z = f2bf(a4) | (f2bf(a5) << 16);
        pk.w = f2bf(a6) | (f2bf(a7) << 16);
      }
      As[row * 16 + (ch ^ (row & 7))] = pk;
    }
  }
  __syncthreads();

  const int w = tid >> 6, l = tid & 63;
  const int hk = l >> 4;                      // 0..3
  const int rl = w * 16 + (l & 15);           // local A row
  const bf16x8* A8 = (const bf16x8*)Ash;
  const bf16x8* W8 = (const bf16x8*)Wsh;

  bf16x8 afr[4];
#pragma unroll
  for (int ks = 0; ks < 4; ++ks)
    afr[ks] = A8[rl * 16 + ((ks * 4 + hk) ^ (rl & 7))];

  f32x4 acc[8];
#pragma unroll
  for (int nf = 0; nf < 8; ++nf) acc[nf] = (f32x4){0.f, 0.f, 0.f, 0.f};

#pragma unroll
  for (int nf = 0; nf < 8; ++nf) {
    int col = nf * 16 + (l & 15);
    int cb = col * 16, cs = col & 7;
#pragma unroll
    for (int ks = 0; ks < 4; ++ks) {
      bf16x8 b = W8[cb + ((ks * 4 + hk) ^ cs)];
      acc[nf] = __builtin_amdgcn_mfma_f32_16x16x32_bf16(afr[ks], b, acc[nf], 0, 0, 0);
    }
  }

  // epilogue: scale by dinv, pack bf16 into Ash (swizzled; wave-disjoint rows)
  float di[4];
  const int rbase = r0 + w * 16 + hk * 4;
#pragma unroll
  for (int r = 0; r < 4; ++r) {
    int gr = rbase + r;
    di[r] = (gr < n) ? dinv[gr] : 0.f;
  }
#pragma unroll
  for (int nf = 0; nf < 8; ++nf) {
    int colb = nf * 16 + (l & 15);
#pragma unroll
    for (int r = 0; r < 4; ++r) {
      int lrow = w * 16 + hk * 4 + r;
      unsigned byteoff = (unsigned)(lrow * 256 + colb * 2);
      byteoff ^= (unsigned)((lrow & 7) << 4);
      *(unsigned short*)((char*)Ash + byteoff) =
          (unsigned short)f2bf(acc[nf][r] * di[r]);
    }
  }
  __syncthreads();

  // coalesced store
  for (int j = tid; j < 1024; j += 256) {
    int row = j >> 4, ch = j & 15;
    int grow = r0 + row;
    if (grow < n) {
      uint4 v = ((const uint4*)Ash)[row * 16 + (ch ^ (row & 7))];
      *(uint4*)&Hout[(size_t)grow * 128 + ch * 8] = v;
    }
  }
}

// ---------------------------------------------------------------------------
// Pull over bf16 rows, fp32 accumulate, 8 gathers in flight.
// FUSE_F=true:  Out = bf16( di * relu( (acc*di + b1) * drop_kd2 ) )   [F pass]
// FUSE_F=false: Out = bf16( di * acc )                                 [G pass]
// ---------------------------------------------------------------------------
template<bool FUSE_F>
__global__ __launch_bounds__(256) void pull128k(
    const unsigned short* __restrict__ H, const int* __restrict__ rowptr,
    const int* __restrict__ adj, const float* __restrict__ dinv,
    const float* __restrict__ bias, unsigned short* __restrict__ Out,
    int n, unsigned k0, unsigned k1)
{
  int wid = (blockIdx.x * 256 + threadIdx.x) >> 6;
  int lane = threadIdx.x & 63;
  if (wid >= n) return;
  int beg = rowptr[wid], end = rowptr[wid + 1];
  const unsigned* Hu = (const unsigned*)H;           // 64 uints per row
  unsigned su = Hu[(size_t)wid * 64 + lane];         // self-loop term
  float2 acc[8];
  acc[0] = make_float2(bf_lo(su), bf_hi(su));
#pragma unroll
  for (int k = 1; k < 8; ++k) acc[k] = make_float2(0.f, 0.f);

  int last = end - 1;
  for (int j = beg; j < end; j += 8) {
    int idx[8];
#pragma unroll
    for (int k = 0; k < 8; ++k) idx[k] = adj[min(j + k, last)];
    unsigned u[8];
#pragma unroll
    for (int k = 0; k < 8; ++k)
      u[k] = Hu[(size_t)idx[k] * 64 + lane];
#pragma unroll
    for (int k = 0; k < 8; ++k) {
      if (j + k <= last) { acc[k].x += bf_lo(u[k]); acc[k].y += bf_hi(u[k]); }
    }
  }

  float sx = ((acc[0].x + acc[1].x) + (acc[2].x + acc[3].x)) +
             ((acc[4].x + acc[5].x) + (acc[6].x + acc[7].x));
  float sy = ((acc[0].y + acc[1].y) + (acc[2].y + acc[3].y)) +
             ((acc[4].y + acc[5].y) + (acc[6].y + acc[7].y));
  float di = dinv[wid];
  unsigned c = (unsigned)lane * 2u;
  float o0, o1;
  if (FUSE_F) {
    float s1a = sx * di + bias[c];
    float s1b = sy * di + bias[c + 1];
    unsigned fb = (unsigned)wid * 128u + c;
    o0 = di * fmaxf(s1a * drop_scale(k0, k1, fb), 0.0f);
    o1 = di * fmaxf(s1b * drop_scale(k0, k1, fb + 1u), 0.0f);
  } else {
    o0 = sx * di;
    o1 = sy * di;
  }
  ((unsigned*)Out)[(size_t)wid * 64 + lane] = f2bf(o0) | (f2bf(o1) << 16);
}

// ---------------------------------------------------------------------------
// Final dense GEMM: out[n][40] = G[n][128](bf16) @ W2[128][40] + b2, fp32 out.
// ---------------------------------------------------------------------------
__global__ __launch_bounds__(256) void gemm_out(
    const unsigned short* __restrict__ G, const float* __restrict__ W2,
    const float* __restrict__ b2, float* __restrict__ out, int n)
{
  __shared__ float Ash[64 * 128];   // 32 KB
  __shared__ float Wsh[32 * 64];    // 8 KB (one K-chunk, cols padded to 64)
  const int tid = threadIdx.x;
  const int r0 = blockIdx.x * 64;
  const uint2* G2 = (const uint2*)G;                 // 32 uint2 per row

  for (int i = tid; i < 64 * 32; i += 256) {
    int rr = i >> 5, q = i & 31;
    int row = r0 + rr;
    uint2 g = make_uint2(0u, 0u);
    if (row < n) g = G2[(size_t)row * 32 + q];
    float* d = &Ash[rr * 128 + q * 4];
    d[0] = bf_lo(g.x); d[1] = bf_hi(g.x);
    d[2] = bf_lo(g.y); d[3] = bf_hi(g.y);
  }

  const int tx = tid & 15, ty = tid >> 4;
  const int c0 = tx * 4;
  const int rl = ty * 4;
  float acc[4][4] = {};
  for (int kb = 0; kb < 4; ++kb) {
    __syncthreads();    // Ash ready (kb=0) / Wsh consumed (kb>0)
    for (int i = tid; i < 2048; i += 256) {
      int r = i >> 6, c = i & 63;
      Wsh[i] = (c < 40) ? W2[(kb * 32 + r) * 40 + c] : 0.0f;
    }
    __syncthreads();
    const int kbase = kb * 32;
    for (int k = 0; k < 32; k += 4) {
      float4 a[4];
#pragma unroll
      for (int i = 0; i < 4; ++i)
        a[i] = *(const float4*)&Ash[(rl + i) * 128 + kbase + k];
#pragma unroll
      for (int kk = 0; kk < 4; ++kk) {
        float4 w = *(const float4*)&Wsh[(k + kk) * 64 + c0];
#pragma unroll
        for (int i = 0; i < 4; ++i) {
          float av = (&a[i].x)[kk];
          acc[i][0] += av * w.x; acc[i][1] += av * w.y;
          acc[i][2] += av * w.z; acc[i][3] += av * w.w;
        }
      }
    }
  }

  if (c0 < 40) {
#pragma unroll
    for (int i = 0; i < 4; ++i) {
      int row = r0 + rl + i;
      if (row < n) {
        float4 o = make_float4(acc[i][0] + b2[c0],     acc[i][1] + b2[c0 + 1],
                               acc[i][2] + b2[c0 + 2], acc[i][3] + b2[c0 + 3]);
        *(float4*)&out[(size_t)row * 40 + c0] = o;     // 160B rows: 16B aligned
      }
    }
  }
}

// ---------------------------------------------------------------------------
extern "C" void kernel_launch(void* const* d_in, const int* in_sizes, int n_in,
                              void* d_out, int out_size, void* d_ws, size_t ws_size,
                              hipStream_t stream) {
  const float* x  = (const float*)d_in[0];
  const int*   ei = (const int*)d_in[1];
  const float* W1 = (const float*)d_in[2];
  const float* b1 = (const float*)d_in[3];
  const float* W2 = (const float*)d_in[4];
  const float* b2 = (const float*)d_in[5];
  const int n = in_sizes[0] / 128;
  const int e = in_sizes[1] / 2;
  const int* src = ei;
  const int* dst = ei + e;

  // kd1, kd2 = jax.random.split(jax.random.key(42))  [fold-like split]
  unsigned kd1a = 0u, kd1b = 0u; tf2x32(0u, 42u, kd1a, kd1b);  // ctr (0,0)
  unsigned kd2a = 0u, kd2b = 1u; tf2x32(0u, 42u, kd2a, kd2b);  // ctr (0,1)

  char* wsp = (char*)d_ws;
  size_t off = 0;
  auto take = [&](size_t bytes) -> char* {
    char* p = wsp + off;
    off = (off + bytes + 255) & ~(size_t)255;
    return p;
  };
  int*   cnt    = (int*)take((size_t)n * 4);
  int*   excl   = (int*)take((size_t)n * 4);
  int*   bsum   = (int*)take(1024);
  int*   rowptr = (int*)take((size_t)(n + 1) * 4);
  float* dinv   = (float*)take((size_t)n * 4);
  int*   adj    = (int*)take((size_t)e * 4);
  unsigned short* Hb = (unsigned short*)take((size_t)n * 128 * 2);  // h1' / G
  unsigned short* Fb = (unsigned short*)take((size_t)n * 128 * 2);  // F
  unsigned short* Wt = (unsigned short*)take(128 * 128 * 2);        // W1^T bf16
  size_t base_off = off;
  int*   rank   = (int*)take((size_t)e * 4);        // fast path only
  bool use_rank = (off <= ws_size);
  int*   cursor = use_rank ? nullptr : (int*)(wsp + base_off);
  (void)n_in; (void)out_size;

  hipMemsetAsync(cnt, 0, (size_t)n * 4, stream);
  if (use_rank) {
    count_rank<<<(e / 4 + 256) / 256, 256, 0, stream>>>(dst, cnt, rank, e);
  } else {
    count_rank<<<(e / 4 + 256) / 256, 256, 0, stream>>>(dst, cnt, cursor, e);
  }
  int nblk = (n + 511) / 512;
  scan_local<<<nblk, 512, 0, stream>>>(cnt, excl, bsum, dinv, n);
  scan_bsum<<<1, 256, 0, stream>>>(bsum, nblk);
  scan_final<<<(n + 256) / 256, 256, 0, stream>>>(excl, bsum, rowptr, cursor,
                                                  n, e, use_rank ? 0 : 1);
  if (use_rank) {
    fill_csr<<<(e / 8 + 256) / 256, 256, 0, stream>>>(src, dst, rank, rowptr, adj, e);
  } else {
    fill_adj_cursor<<<(e / 4 + 256) / 256, 256, 0, stream>>>(src, dst, cursor, adj, e);
  }

  // W1 -> bf16 transpose (tiny)
  w1t_bf16<<<64, 256, 0, stream>>>(W1, Wt);

  // layer 1 via MFMA: h1' = bf16(dinv * (relu(drop_kd1(x)) @ W1))
  gemm_l1_mfma<<<(n + 63) / 64, 256, 0, stream>>>(x, Wt, dinv, Hb, n, kd1a, kd1b);

  // F = bf16(dinv * relu(drop_kd2(pull(h1') + b1)))
  pull128k<true><<<(n + 3) / 4, 256, 0, stream>>>(Hb, rowptr, adj, dinv, b1,
                                                  Fb, n, kd2a, kd2b);

  // G = bf16(dinv * (pull(F)))   [aggregation commutes with @W2]
  pull128k<false><<<(n + 3) / 4, 256, 0, stream>>>(Fb, rowptr, adj, dinv, b1,
                                                   Hb, n, 0u, 0u);

  // out = G @ W2 + b2
  gemm_out<<<(n + 63) / 64, 256, 0, stream>>>(Hb, W2, b2, (float*)d_out, n);
}

// Round 11
// 406.782 us; speedup vs baseline: 1.3791x; 1.0771x over previous
//
#include <hip/hip_runtime.h>
#include <stdint.h>

typedef __attribute__((ext_vector_type(8))) short bf16x8;
typedef __attribute__((ext_vector_type(4))) float f32x4;

// ---------------------------------------------------------------------------
// Threefry-2x32 (20 rounds) — exact JAX semantics.
// ---------------------------------------------------------------------------
__host__ __device__ inline void tf2x32(unsigned k0, unsigned k1,
                                       unsigned& x0, unsigned& x1) {
  unsigned k2 = k0 ^ k1 ^ 0x1BD11BDAu;
  x0 += k0; x1 += k1;
#define TFR(r) { x0 += x1; x1 = (x1 << (r)) | (x1 >> (32 - (r))); x1 ^= x0; }
  TFR(13) TFR(15) TFR(26) TFR(6)
  x0 += k1; x1 += k2 + 1u;
  TFR(17) TFR(29) TFR(16) TFR(24)
  x0 += k2; x1 += k0 + 2u;
  TFR(13) TFR(15) TFR(26) TFR(6)
  x0 += k0; x1 += k1 + 3u;
  TFR(17) TFR(29) TFR(16) TFR(24)
  x0 += k1; x1 += k2 + 4u;
  TFR(13) TFR(15) TFR(26) TFR(6)
  x0 += k2; x1 += k0 + 5u;
#undef TFR
}

__device__ __forceinline__ float drop_scale(unsigned k0, unsigned k1, unsigned f) {
  unsigned a = 0u, b = f;
  tf2x32(k0, k1, a, b);
  unsigned bits = a ^ b;
  float u = __uint_as_float((bits >> 9) | 0x3f800000u) - 1.0f;
  return (u < 0.8f) ? 1.25f : 0.0f;
}

// fp32 -> bf16 (RNE) and unpack helpers
__device__ __forceinline__ unsigned f2bf(float x) {
  unsigned u = __float_as_uint(x);
  return (u + 0x7fffu + ((u >> 16) & 1u)) >> 16;
}
__device__ __forceinline__ float bf_lo(unsigned u) { return __uint_as_float(u << 16); }
__device__ __forceinline__ float bf_hi(unsigned u) { return __uint_as_float(u & 0xffff0000u); }

// ---------------------------------------------------------------------------
// CSR build: count+rank -> scan -> atomic-free fill
// ---------------------------------------------------------------------------
__global__ __launch_bounds__(256) void count_rank(
    const int* __restrict__ dst, int* __restrict__ cnt,
    int* __restrict__ rank, int e) {
  int i0 = (blockIdx.x * 256 + threadIdx.x) * 4;
  if (i0 + 3 < e) {
    int4 d4 = *(const int4*)&dst[i0];
    int4 r4;
    r4.x = atomicAdd(&cnt[d4.x], 1);
    r4.y = atomicAdd(&cnt[d4.y], 1);
    r4.z = atomicAdd(&cnt[d4.z], 1);
    r4.w = atomicAdd(&cnt[d4.w], 1);
    *(int4*)&rank[i0] = r4;
  } else {
    for (int i = i0; i < e; ++i)
      rank[i] = atomicAdd(&cnt[dst[i]], 1);
  }
}

__global__ __launch_bounds__(256) void fill_adj_cursor(
    const int* __restrict__ src, const int* __restrict__ dst,
    int* __restrict__ cursor, int* __restrict__ adj, int e) {
  int i0 = (blockIdx.x * 256 + threadIdx.x) * 4;
  for (int i = i0; i < min(i0 + 4, e); ++i) {
    int d = dst[i];
    int p = atomicAdd(&cursor[d], 1);
    adj[p] = src[i];
  }
}

__global__ void scan_local(const int* __restrict__ cnt, int* __restrict__ excl,
                           int* __restrict__ bsum, float* __restrict__ dinv, int n) {
  __shared__ int sh[512];
  int i = blockIdx.x * 512 + threadIdx.x;
  int v = (i < n) ? cnt[i] : 0;
  if (i < n) dinv[i] = 1.0f / sqrtf((float)v + 1.0f);
  sh[threadIdx.x] = v;
  __syncthreads();
  for (int d = 1; d < 512; d <<= 1) {
    int t = (threadIdx.x >= d) ? sh[threadIdx.x - d] : 0;
    __syncthreads();
    sh[threadIdx.x] += t;
    __syncthreads();
  }
  if (i < n) excl[i] = sh[threadIdx.x] - v;
  if (threadIdx.x == 511) bsum[blockIdx.x] = sh[511];
}

__global__ void scan_bsum(int* __restrict__ bsum, int nb) {
  __shared__ int sh[256];
  int tid = threadIdx.x;
  int v = (tid < nb) ? bsum[tid] : 0;
  sh[tid] = v;
  __syncthreads();
  for (int d = 1; d < 256; d <<= 1) {
    int t = (tid >= d) ? sh[tid - d] : 0;
    __syncthreads();
    sh[tid] += t;
    __syncthreads();
  }
  if (tid < nb) bsum[tid] = sh[tid] - v;
}

__global__ void scan_final(const int* __restrict__ excl, const int* __restrict__ bsum,
                           int* __restrict__ rowptr, int* __restrict__ cursor,
                           int n, int e, int write_cursor) {
  int i = blockIdx.x * blockDim.x + threadIdx.x;
  if (i < n) {
    int r = excl[i] + bsum[i >> 9];
    rowptr[i] = r;
    if (write_cursor) cursor[i] = r;
  }
  if (i == n) rowptr[n] = e;
}

__global__ __launch_bounds__(256) void fill_csr(
    const int* __restrict__ src, const int* __restrict__ dst,
    const int* __restrict__ rank, const int* __restrict__ rowptr,
    int* __restrict__ adj, int e) {
  int i0 = (blockIdx.x * 256 + threadIdx.x) * 8;
  if (i0 + 7 < e) {
    int4 d0 = *(const int4*)&dst[i0];
    int4 d1 = *(const int4*)&dst[i0 + 4];
    int4 r0 = *(const int4*)&rank[i0];
    int4 r1 = *(const int4*)&rank[i0 + 4];
    int4 s0 = *(const int4*)&src[i0];
    int4 s1 = *(const int4*)&src[i0 + 4];
    int p0 = rowptr[d0.x] + r0.x;
    int p1 = rowptr[d0.y] + r0.y;
    int p2 = rowptr[d0.z] + r0.z;
    int p3 = rowptr[d0.w] + r0.w;
    int p4 = rowptr[d1.x] + r1.x;
    int p5 = rowptr[d1.y] + r1.y;
    int p6 = rowptr[d1.z] + r1.z;
    int p7 = rowptr[d1.w] + r1.w;
    adj[p0] = s0.x; adj[p1] = s0.y; adj[p2] = s0.z; adj[p3] = s0.w;
    adj[p4] = s1.x; adj[p5] = s1.y; adj[p6] = s1.z; adj[p7] = s1.w;
  } else {
    for (int i = i0; i < e; ++i)
      adj[rowptr[dst[i]] + rank[i]] = src[i];
  }
}

// ---------------------------------------------------------------------------
// Prep: W1 (fp32 [k][c]) -> Wt (bf16 [c][k]) for MFMA B-operand staging.
// ---------------------------------------------------------------------------
__global__ __launch_bounds__(256) void w1t_bf16(
    const float* __restrict__ W, unsigned short* __restrict__ Wt) {
  int i = blockIdx.x * 256 + threadIdx.x;       // 16384 elements
  int k = i >> 7, c = i & 127;
  Wt[c * 128 + k] = (unsigned short)f2bf(W[i]);
}

// ---------------------------------------------------------------------------
// Layer-1 GEMM via bf16 MFMA (16x16x32). See round-9 notes for layouts.
// ---------------------------------------------------------------------------
__global__ __launch_bounds__(256) void gemm_l1_mfma(
    const float* __restrict__ A, const unsigned short* __restrict__ Wt,
    const float* __restrict__ dinv, unsigned short* __restrict__ Hout,
    int n, unsigned kd0, unsigned kd1)
{
  __shared__ unsigned short Ash[64 * 128];    // 16 KB
  __shared__ unsigned short Wsh[128 * 128];   // 32 KB
  const int tid = threadIdx.x;
  const int r0 = blockIdx.x * 64;

  // stage Wt -> Wsh (swizzled), 2048 x 16B chunks
  {
    const uint4* Wg = (const uint4*)Wt;
    uint4* Ws = (uint4*)Wsh;
    for (int j = tid; j < 2048; j += 256) {
      int row = j >> 4, ch = j & 15;
      Ws[row * 16 + (ch ^ (row & 7))] = Wg[j];
    }
  }

  // stage A -> Ash (dropout+relu+cvt, swizzled), 1024 x 16B chunks (8 bf16)
  {
    uint4* As = (uint4*)Ash;
    for (int j = tid; j < 1024; j += 256) {
      int row = j >> 4, ch = j & 15;
      int grow = r0 + row;
      uint4 pk = make_uint4(0u, 0u, 0u, 0u);
      if (grow < n) {
        const float4* p = (const float4*)&A[(size_t)grow * 128 + ch * 8];
        float4 f0 = p[0], f1 = p[1];
        unsigned fb = (unsigned)grow * 128u + (unsigned)(ch * 8);
        float a0 = fmaxf(f0.x, 0.f) * drop_scale(kd0, kd1, fb + 0u);
        float a1 = fmaxf(f0.y, 0.f) * drop_scale(kd0, kd1, fb + 1u);
        float a2 = fmaxf(f0.z, 0.f) * drop_scale(kd0, kd1, fb + 2u);
        float a3 = fmaxf(f0.w, 0.f) * drop_scale(kd0, kd1, fb + 3u);
        float a4 = fmaxf(f1.x, 0.f) * drop_scale(kd0, kd1, fb + 4u);
        float a5 = fmaxf(f1.y, 0.f) * drop_scale(kd0, kd1, fb + 5u);
        float a6 = fmaxf(f1.z, 0.f) * drop_scale(kd0, kd1, fb + 6u);
        float a7 = fmaxf(f1.w, 0.f) * drop_scale(kd0, kd1, fb + 7u);
        pk.x = f2bf(a0) | (f2bf(a1) << 16);
        pk.y = f2bf(a2) | (f2bf(a3) << 16);
        pk.z = f2bf(a4) | (f2bf(a5) << 16);
        pk.w = f2bf(a6) | (f2bf(a7) << 16);
      }
      As[row * 16 + (ch ^ (row & 7))] = pk;
    }
  }
  __syncthreads();

  const int w = tid >> 6, l = tid & 63;
  const int hk = l >> 4;                      // 0..3
  const int rl = w * 16 + (l & 15);           // local A row
  const bf16x8* A8 = (const bf16x8*)Ash;
  const bf16x8* W8 = (const bf16x8*)Wsh;

  bf16x8 afr[4];
#pragma unroll
  for (int ks = 0; ks < 4; ++ks)
    afr[ks] = A8[rl * 16 + ((ks * 4 + hk) ^ (rl & 7))];

  f32x4 acc[8];
#pragma unroll
  for (int nf = 0; nf < 8; ++nf) acc[nf] = (f32x4){0.f, 0.f, 0.f, 0.f};

#pragma unroll
  for (int nf = 0; nf < 8; ++nf) {
    int col = nf * 16 + (l & 15);
    int cb = col * 16, cs = col & 7;
#pragma unroll
    for (int ks = 0; ks < 4; ++ks) {
      bf16x8 b = W8[cb + ((ks * 4 + hk) ^ cs)];
      acc[nf] = __builtin_amdgcn_mfma_f32_16x16x32_bf16(afr[ks], b, acc[nf], 0, 0, 0);
    }
  }

  // epilogue: scale by dinv, pack bf16 into Ash (swizzled; wave-disjoint rows)
  float di[4];
  const int rbase = r0 + w * 16 + hk * 4;
#pragma unroll
  for (int r = 0; r < 4; ++r) {
    int gr = rbase + r;
    di[r] = (gr < n) ? dinv[gr] : 0.f;
  }
#pragma unroll
  for (int nf = 0; nf < 8; ++nf) {
    int colb = nf * 16 + (l & 15);
#pragma unroll
    for (int r = 0; r < 4; ++r) {
      int lrow = w * 16 + hk * 4 + r;
      unsigned byteoff = (unsigned)(lrow * 256 + colb * 2);
      byteoff ^= (unsigned)((lrow & 7) << 4);
      *(unsigned short*)((char*)Ash + byteoff) =
          (unsigned short)f2bf(acc[nf][r] * di[r]);
    }
  }
  __syncthreads();

  // coalesced store
  for (int j = tid; j < 1024; j += 256) {
    int row = j >> 4, ch = j & 15;
    int grow = r0 + row;
    if (grow < n) {
      uint4 v = ((const uint4*)Ash)[row * 16 + (ch ^ (row & 7))];
      *(uint4*)&Hout[(size_t)grow * 128 + ch * 8] = v;
    }
  }
}

// ---------------------------------------------------------------------------
// Pull over bf16 rows, fp32 accumulate, 8 gathers in flight.
// SCALARIZED: wid/beg/end/idx are wave-uniform -> readfirstlane moves the
// whole per-edge address chain to SALU; gathers become
// global_load_dword v, v_laneoff, s[rowbase]. VALU per edge = unpack+add only.
// FUSE_F=true:  Out = bf16( di * relu( (acc*di + b1) * drop_kd2 ) )   [F pass]
// FUSE_F=false: Out = bf16( di * acc )                                 [G pass]
// ---------------------------------------------------------------------------
template<bool FUSE_F>
__global__ __launch_bounds__(256) void pull128k(
    const unsigned short* __restrict__ H, const int* __restrict__ rowptr,
    const int* __restrict__ adj, const float* __restrict__ dinv,
    const float* __restrict__ bias, unsigned short* __restrict__ Out,
    int n, unsigned k0, unsigned k1)
{
  int wid = (blockIdx.x * 256 + threadIdx.x) >> 6;
  int lane = threadIdx.x & 63;
  if (wid >= n) return;
  wid = __builtin_amdgcn_readfirstlane(wid);
  const int beg = __builtin_amdgcn_readfirstlane(rowptr[wid]);
  const int end = __builtin_amdgcn_readfirstlane(rowptr[wid + 1]);
  const unsigned* Hu = (const unsigned*)H;           // 64 uints per row
  unsigned su = Hu[(size_t)wid * 64 + lane];         // self-loop term
  float2 acc[8];
  acc[0] = make_float2(bf_lo(su), bf_hi(su));
#pragma unroll
  for (int k = 1; k < 8; ++k) acc[k] = make_float2(0.f, 0.f);

  int j = beg;
  // full batches, no masking
  for (; j + 8 <= end; j += 8) {
    int sidx[8];
#pragma unroll
    for (int k = 0; k < 8; ++k)
      sidx[k] = __builtin_amdgcn_readfirstlane(adj[j + k]);
    unsigned u[8];
#pragma unroll
    for (int k = 0; k < 8; ++k)
      u[k] = Hu[(size_t)(unsigned)sidx[k] * 64 + lane];
#pragma unroll
    for (int k = 0; k < 8; ++k) {
      acc[k].x += bf_lo(u[k]);
      acc[k].y += bf_hi(u[k]);
    }
  }
  // masked tail (wave-uniform conditions)
  if (j < end) {
    int last = end - 1;
    int sidx[8];
#pragma unroll
    for (int k = 0; k < 8; ++k)
      sidx[k] = __builtin_amdgcn_readfirstlane(adj[min(j + k, last)]);
    unsigned u[8];
#pragma unroll
    for (int k = 0; k < 8; ++k)
      u[k] = Hu[(size_t)(unsigned)sidx[k] * 64 + lane];
#pragma unroll
    for (int k = 0; k < 8; ++k) {
      if (j + k <= last) { acc[k].x += bf_lo(u[k]); acc[k].y += bf_hi(u[k]); }
    }
  }

  float sx = ((acc[0].x + acc[1].x) + (acc[2].x + acc[3].x)) +
             ((acc[4].x + acc[5].x) + (acc[6].x + acc[7].x));
  float sy = ((acc[0].y + acc[1].y) + (acc[2].y + acc[3].y)) +
             ((acc[4].y + acc[5].y) + (acc[6].y + acc[7].y));
  float di = __builtin_amdgcn_readfirstlane(__float_as_uint(dinv[wid])) != 0
                 ? dinv[wid] : dinv[wid];   // keep simple: plain load below
  di = dinv[wid];
  unsigned c = (unsigned)lane * 2u;
  float o0, o1;
  if (FUSE_F) {
    float s1a = sx * di + bias[c];
    float s1b = sy * di + bias[c + 1];
    unsigned fb = (unsigned)wid * 128u + c;
    o0 = di * fmaxf(s1a * drop_scale(k0, k1, fb), 0.0f);
    o1 = di * fmaxf(s1b * drop_scale(k0, k1, fb + 1u), 0.0f);
  } else {
    o0 = sx * di;
    o1 = sy * di;
  }
  ((unsigned*)Out)[(size_t)wid * 64 + lane] = f2bf(o0) | (f2bf(o1) << 16);
}

// ---------------------------------------------------------------------------
// Final dense GEMM: out[n][40] = G[n][128](bf16) @ W2[128][40] + b2, fp32 out.
// ---------------------------------------------------------------------------
__global__ __launch_bounds__(256) void gemm_out(
    const unsigned short* __restrict__ G, const float* __restrict__ W2,
    const float* __restrict__ b2, float* __restrict__ out, int n)
{
  __shared__ float Ash[64 * 128];   // 32 KB
  __shared__ float Wsh[32 * 64];    // 8 KB (one K-chunk, cols padded to 64)
  const int tid = threadIdx.x;
  const int r0 = blockIdx.x * 64;
  const uint2* G2 = (const uint2*)G;                 // 32 uint2 per row

  for (int i = tid; i < 64 * 32; i += 256) {
    int rr = i >> 5, q = i & 31;
    int row = r0 + rr;
    uint2 g = make_uint2(0u, 0u);
    if (row < n) g = G2[(size_t)row * 32 + q];
    float* d = &Ash[rr * 128 + q * 4];
    d[0] = bf_lo(g.x); d[1] = bf_hi(g.x);
    d[2] = bf_lo(g.y); d[3] = bf_hi(g.y);
  }

  const int tx = tid & 15, ty = tid >> 4;
  const int c0 = tx * 4;
  const int rl = ty * 4;
  float acc[4][4] = {};
  for (int kb = 0; kb < 4; ++kb) {
    __syncthreads();    // Ash ready (kb=0) / Wsh consumed (kb>0)
    for (int i = tid; i < 2048; i += 256) {
      int r = i >> 6, c = i & 63;
      Wsh[i] = (c < 40) ? W2[(kb * 32 + r) * 40 + c] : 0.0f;
    }
    __syncthreads();
    const int kbase = kb * 32;
    for (int k = 0; k < 32; k += 4) {
      float4 a[4];
#pragma unroll
      for (int i = 0; i < 4; ++i)
        a[i] = *(const float4*)&Ash[(rl + i) * 128 + kbase + k];
#pragma unroll
      for (int kk = 0; kk < 4; ++kk) {
        float4 w = *(const float4*)&Wsh[(k + kk) * 64 + c0];
#pragma unroll
        for (int i = 0; i < 4; ++i) {
          float av = (&a[i].x)[kk];
          acc[i][0] += av * w.x; acc[i][1] += av * w.y;
          acc[i][2] += av * w.z; acc[i][3] += av * w.w;
        }
      }
    }
  }

  if (c0 < 40) {
#pragma unroll
    for (int i = 0; i < 4; ++i) {
      int row = r0 + rl + i;
      if (row < n) {
        float4 o = make_float4(acc[i][0] + b2[c0],     acc[i][1] + b2[c0 + 1],
                               acc[i][2] + b2[c0 + 2], acc[i][3] + b2[c0 + 3]);
        *(float4*)&out[(size_t)row * 40 + c0] = o;     // 160B rows: 16B aligned
      }
    }
  }
}

// ---------------------------------------------------------------------------
extern "C" void kernel_launch(void* const* d_in, const int* in_sizes, int n_in,
                              void* d_out, int out_size, void* d_ws, size_t ws_size,
                              hipStream_t stream) {
  const float* x  = (const float*)d_in[0];
  const int*   ei = (const int*)d_in[1];
  const float* W1 = (const float*)d_in[2];
  const float* b1 = (const float*)d_in[3];
  const float* W2 = (const float*)d_in[4];
  const float* b2 = (const float*)d_in[5];
  const int n = in_sizes[0] / 128;
  const int e = in_sizes[1] / 2;
  const int* src = ei;
  const int* dst = ei + e;

  // kd1, kd2 = jax.random.split(jax.random.key(42))  [fold-like split]
  unsigned kd1a = 0u, kd1b = 0u; tf2x32(0u, 42u, kd1a, kd1b);  // ctr (0,0)
  unsigned kd2a = 0u, kd2b = 1u; tf2x32(0u, 42u, kd2a, kd2b);  // ctr (0,1)

  char* wsp = (char*)d_ws;
  size_t off = 0;
  auto take = [&](size_t bytes) -> char* {
    char* p = wsp + off;
    off = (off + bytes + 255) & ~(size_t)255;
    return p;
  };
  int*   cnt    = (int*)take((size_t)n * 4);
  int*   excl   = (int*)take((size_t)n * 4);
  int*   bsum   = (int*)take(1024);
  int*   rowptr = (int*)take((size_t)(n + 1) * 4);
  float* dinv   = (float*)take((size_t)n * 4);
  int*   adj    = (int*)take((size_t)e * 4);
  unsigned short* Hb = (unsigned short*)take((size_t)n * 128 * 2);  // h1' / G
  unsigned short* Fb = (unsigned short*)take((size_t)n * 128 * 2);  // F
  unsigned short* Wt = (unsigned short*)take(128 * 128 * 2);        // W1^T bf16
  size_t base_off = off;
  int*   rank   = (int*)take((size_t)e * 4);        // fast path only
  bool use_rank = (off <= ws_size);
  int*   cursor = use_rank ? nullptr : (int*)(wsp + base_off);
  (void)n_in; (void)out_size;

  hipMemsetAsync(cnt, 0, (size_t)n * 4, stream);
  if (use_rank) {
    count_rank<<<(e / 4 + 256) / 256, 256, 0, stream>>>(dst, cnt, rank, e);
  } else {
    count_rank<<<(e / 4 + 256) / 256, 256, 0, stream>>>(dst, cnt, cursor, e);
  }
  int nblk = (n + 511) / 512;
  scan_local<<<nblk, 512, 0, stream>>>(cnt, excl, bsum, dinv, n);
  scan_bsum<<<1, 256, 0, stream>>>(bsum, nblk);
  scan_final<<<(n + 256) / 256, 256, 0, stream>>>(excl, bsum, rowptr, cursor,
                                                  n, e, use_rank ? 0 : 1);
  if (use_rank) {
    fill_csr<<<(e / 8 + 256) / 256, 256, 0, stream>>>(src, dst, rank, rowptr, adj, e);
  } else {
    fill_adj_cursor<<<(e / 4 + 256) / 256, 256, 0, stream>>>(src, dst, cursor, adj, e);
  }

  // W1 -> bf16 transpose (tiny)
  w1t_bf16<<<64, 256, 0, stream>>>(W1, Wt);

  // layer 1 via MFMA: h1' = bf16(dinv * (relu(drop_kd1(x)) @ W1))
  gemm_l1_mfma<<<(n + 63) / 64, 256, 0, stream>>>(x, Wt, dinv, Hb, n, kd1a, kd1b);

  // F = bf16(dinv * relu(drop_kd2(pull(h1') + b1)))
  pull128k<true><<<(n + 3) / 4, 256, 0, stream>>>(Hb, rowptr, adj, dinv, b1,
                                                  Fb, n, kd2a, kd2b);

  // G = bf16(dinv * (pull(F)))   [aggregation commutes with @W2]
  pull128k<false><<<(n + 3) / 4, 256, 0, stream>>>(Fb, rowptr, adj, dinv, b1,
                                                   Hb, n, 0u, 0u);

  // out = G @ W2 + b2
  gemm_out<<<(n + 63) / 64, 256, 0, stream>>>(Hb, W2, b2, (float*)d_out, n);
}